// Round 3
// baseline (676.211 us; speedup 1.0000x reference)
//
#include <hip/hip_runtime.h>

// Problem: batch=8, seq=16384, d=256, hidden=32, 14 levels, 10 transforms.
// ALL TENSORS ARE FLOAT32 (reference uses jnp.float32 throughout).
//
// Math restructure: the level-l update At_l is constant within each group, so
// everything lives on a mean pyramid:
//   A_0[r]    = 0.5*(Z[2r] + Z[2r+1])
//   At_l      = MLP_t(A_l)            (overwrites A_l in place)
//   A_{l+1}[g]= 0.5*((A_l+At_l)[2g] + (A_l+At_l)[2g+1])
//   out[b,s]  = Z[b,s] + sum_l At_l[b, s>>(l+1)]
// Pyramid: level l has 65536>>l rows of 256 f32; row-offset of level l is
// 131072-(131072>>l); total 131064 rows = 33,552,384 f32 = 134,209,536 B.
// Lives in d_ws if ws_size permits, else in d_out (fits: out is 134,217,728 B).

// jax.nn.gelu default approximate=True (tanh form)
__device__ __forceinline__ float gelu_t(float x){
  float t = tanhf(0.7978845608028654f * (x + 0.044715f * x * x * x));
  return 0.5f * x * (1.0f + t);
}

// ---------- kernel 1: level-0 pairwise means: P0[r] = 0.5*(Z[2r]+Z[2r+1]) ----------
__global__ void __launch_bounds__(256) k_mean0(const float* __restrict__ Z,
                                               float* __restrict__ P0){
  long t = (long)blockIdx.x * 256 + threadIdx.x;   // 4,194,304 threads, 4 f32 each
  long base = t * 4;                                // elem index in P0 (16,777,216)
  long row  = base >> 8;                            // b*8192 + g
  int  d    = (int)(base & 255);
  float4 a = *(const float4*)(Z + ((2*row)   << 8) + d);
  float4 b = *(const float4*)(Z + ((2*row+1) << 8) + d);
  float4 o;
  o.x = 0.5f*(a.x+b.x); o.y = 0.5f*(a.y+b.y);
  o.z = 0.5f*(a.z+b.z); o.w = 0.5f*(a.w+b.w);
  *(float4*)(P0 + base) = o;
}

// ---------- kernel 2: per-level MLP (in-place At) + next-level means ----------
#define RB 32        // rows (groups) per block
#define SA 260       // LDS row stride in f32: 1040 B (16B-aligned, 4-bank skew/row)
__global__ void __launch_bounds__(256) k_mlp(
    float* __restrict__ Pio, float* __restrict__ Pnext,
    const float* __restrict__ W1, const float* __restrict__ B1,
    const float* __restrict__ W2, const float* __restrict__ B2,
    int nrows, int donext)
{
  __shared__ __align__(16) float a_s [RB * SA];   // A rows
  __shared__ __align__(16) float w1t [32 * SA];   // W1 transposed: [j][d]
  __shared__ __align__(16) float w2s [32 * SA];   // W2 natural:    [j][d]
  __shared__ float h_s[RB * 33];
  __shared__ float b1s[32];
  __shared__ float b2s[256];
  const int tid  = threadIdx.x;
  const int row0 = blockIdx.x * RB;

  // stage A rows (zero-pad past nrows): 2048 float4 tasks
  for(int c = tid; c < 2048; c += 256){
    int r = c >> 6, q = c & 63;                   // q: float4 index within row
    int row = row0 + r;
    float4 v = make_float4(0.f,0.f,0.f,0.f);
    if(row < nrows) v = *(const float4*)(Pio + ((long)row << 8) + q*4);
    *(float4*)&a_s[r*SA + q*4] = v;
  }
  // stage W1 transposed (W1 is [d][j], j fastest): 2048 float4 tasks
  for(int c = tid; c < 2048; c += 256){
    int d = c >> 3, j0 = (c & 7) * 4;
    float4 w = *(const float4*)(W1 + d*32 + j0);
    w1t[(j0+0)*SA + d] = w.x;
    w1t[(j0+1)*SA + d] = w.y;
    w1t[(j0+2)*SA + d] = w.z;
    w1t[(j0+3)*SA + d] = w.w;
  }
  // stage W2 ([j][d], d fastest): 2048 float4 tasks
  for(int c = tid; c < 2048; c += 256){
    int j = c >> 6, q = c & 63;
    *(float4*)&w2s[j*SA + q*4] = *(const float4*)(W2 + j*256 + q*4);
  }
  if(tid < 32) b1s[tid] = B1[tid];
  b2s[tid] = B2[tid];
  __syncthreads();

  // phase h: h[r][j] = gelu(A[r]·W1[:,j] + b1[j]); 2x2 blocking (r,r+16)x(j,j+16)
  {
    const int rp = tid >> 4, jp = tid & 15;
    float acc00 = b1s[jp], acc01 = b1s[jp+16];
    float acc10 = b1s[jp], acc11 = b1s[jp+16];
    const float4* pa0 = (const float4*)&a_s[ rp     * SA];
    const float4* pa1 = (const float4*)&a_s[(rp+16) * SA];
    const float4* pw0 = (const float4*)&w1t[ jp     * SA];
    const float4* pw1 = (const float4*)&w1t[(jp+16) * SA];
    #pragma unroll 8
    for(int k4 = 0; k4 < 64; k4++){
      float4 a0 = pa0[k4], a1 = pa1[k4], w0 = pw0[k4], w1 = pw1[k4];
      acc00 += a0.x*w0.x + a0.y*w0.y + a0.z*w0.z + a0.w*w0.w;
      acc01 += a0.x*w1.x + a0.y*w1.y + a0.z*w1.z + a0.w*w1.w;
      acc10 += a1.x*w0.x + a1.y*w0.y + a1.z*w0.z + a1.w*w0.w;
      acc11 += a1.x*w1.x + a1.y*w1.y + a1.z*w1.z + a1.w*w1.w;
    }
    h_s[ rp    *33 + jp   ] = gelu_t(acc00);
    h_s[ rp    *33 + jp+16] = gelu_t(acc01);
    h_s[(rp+16)*33 + jp   ] = gelu_t(acc10);
    h_s[(rp+16)*33 + jp+16] = gelu_t(acc11);
  }
  __syncthreads();

  // phase At: At[r] = h[r]·W2 + b2 (overwrite Pio row); Pnext[r/2] = mean of updated pair
  for(int task = tid; task < 512; task += 256){
    int rpair = task >> 5, d8 = task & 31;        // 8 f32 per task
    int r0 = rpair*2, r1 = r0 + 1;
    long g0 = row0 + r0, g1 = row0 + r1;
    if(g0 >= nrows) continue;                     // nrows even at every level
    float acc0[8], acc1[8];
    #pragma unroll
    for(int k=0;k<8;k++){ acc0[k] = b2s[d8*8+k]; acc1[k] = acc0[k]; }
    #pragma unroll 8
    for(int j=0;j<32;j++){
      float h0 = h_s[r0*33+j], h1 = h_s[r1*33+j];
      const float* w = &w2s[j*SA + d8*8];
      #pragma unroll
      for(int k=0;k<8;k++){ float wf = w[k]; acc0[k] += h0*wf; acc1[k] += h1*wf; }
    }
    #pragma unroll
    for(int k=0;k<4;k++){ ((float4*)(Pio + (g0<<8) + d8*8))[0] = *(float4*)&acc0[0]; break; }
    *(float4*)(Pio + (g0<<8) + d8*8)     = *(float4*)&acc0[0];
    *(float4*)(Pio + (g0<<8) + d8*8 + 4) = *(float4*)&acc0[4];
    *(float4*)(Pio + (g1<<8) + d8*8)     = *(float4*)&acc1[0];
    *(float4*)(Pio + (g1<<8) + d8*8 + 4) = *(float4*)&acc1[4];
    if(donext){
      float m[8];
      #pragma unroll
      for(int k=0;k<8;k++){
        float u0 = a_s[r0*SA + d8*8 + k] + acc0[k];
        float u1 = a_s[r1*SA + d8*8 + k] + acc1[k];
        m[k] = 0.5f*(u0 + u1);
      }
      *(float4*)(Pnext + ((g0>>1)<<8) + d8*8)     = *(float4*)&m[0];
      *(float4*)(Pnext + ((g0>>1)<<8) + d8*8 + 4) = *(float4*)&m[4];
    }
  }
}

// ---------- kernel 3: out[b,s] = Z[b,s] + sum_l At_l[b, s>>(l+1)] ----------
// (out may alias Z: each thread reads/writes only its own elements)
__global__ void __launch_bounds__(256) k_final(const float* __restrict__ Z,
                                               const float* __restrict__ P,
                                               float* __restrict__ out){
  long t = (long)blockIdx.x * 256 + threadIdx.x;  // 8,388,608 threads, 4 f32 each
  long base = t * 4;
  long row  = base >> 8;                          // b*16384 + s
  int  doff = (int)(base & 255);
  int  b = (int)(row >> 14), s = (int)(row & 16383);
  float4 acc = *(const float4*)(Z + base);
  #pragma unroll
  for(int l = 0; l < 14; l++){
    int rowoff = 131072 - (131072 >> l);          // rows before level l
    int g = s >> (l + 1);
    long p = ((long)(rowoff + (b << (13 - l)) + g) << 8) + doff;
    float4 f = *(const float4*)(P + p);
    acc.x += f.x; acc.y += f.y; acc.z += f.z; acc.w += f.w;
  }
  *(float4*)(out + base) = acc;
}

extern "C" void kernel_launch(void* const* d_in, const int* in_sizes, int n_in,
                              void* d_out, int out_size, void* d_ws, size_t ws_size,
                              hipStream_t stream) {
  const float* Z  = (const float*)d_in[0];
  const float* W1 = (const float*)d_in[1];
  const float* B1 = (const float*)d_in[2];
  const float* W2 = (const float*)d_in[3];
  const float* B2 = (const float*)d_in[4];

  const size_t pyr_elems = 33552384;              // 131064 rows * 256
  const bool   use_ws    = ws_size >= pyr_elems * sizeof(float);
  float* P = use_ws ? (float*)d_ws : (float*)d_out;   // pyramid fits in d_out too

  k_mean0<<<16384, 256, 0, stream>>>(Z, P);

  long off = 0;
  for(int l = 0; l < 14; l++){
    int nrows = 65536 >> l;                       // 8 * (8192 >> l)
    long offn = off + (long)nrows * 256;
    int t = (l < 9) ? l : 9;
    int blocks = (nrows + RB - 1) / RB;
    k_mlp<<<blocks, 256, 0, stream>>>(P + off, P + offn,
                                      W1 + (long)t*8192, B1 + (long)t*32,
                                      W2 + (long)t*8192, B2 + (long)t*256,
                                      nrows, (l < 13) ? 1 : 0);
    off = offn;
  }

  if(use_ws){
    // pyramid in d_ws: write result straight to d_out
    k_final<<<32768, 256, 0, stream>>>(Z, P, (float*)d_out);
  }else{
    // pyramid occupies d_out: accumulate into Z's buffer in place (harness
    // restores inputs from pristine copies before every launch), then D2D copy
    k_final<<<32768, 256, 0, stream>>>(Z, P, (float*)d_in[0]);
    hipMemcpyAsync(d_out, d_in[0], (size_t)out_size * sizeof(float),
                   hipMemcpyDeviceToDevice, stream);
  }
}